// Round 2
// baseline (1112.650 us; speedup 1.0000x reference)
//
#include <hip/hip_runtime.h>
#include <math.h>

#define DIM 64

__device__ __forceinline__ float leaky(float e) { return e > 0.f ? e : 0.2f * e; }

// ---------------- CSR build ----------------
__global__ void k_deg_init(int* deg, int n) {
    int i = blockIdx.x * blockDim.x + threadIdx.x;
    if (i < n) deg[i] = 1;  // self loop
}

__global__ void k_deg_count(const int* __restrict__ ei, int* deg, int E) {
    int i = blockIdx.x * blockDim.x + threadIdx.x;
    if (i < E) atomicAdd(&deg[ei[E + i]], 1);
}

__global__ void k_scan_block(const int* __restrict__ deg, int* excl, int* bsum, int n) {
    __shared__ int tmp[256];
    int i = blockIdx.x * 256 + threadIdx.x;
    int v = (i < n) ? deg[i] : 0;
    tmp[threadIdx.x] = v;
    __syncthreads();
    for (int off = 1; off < 256; off <<= 1) {
        int t = (threadIdx.x >= off) ? tmp[threadIdx.x - off] : 0;
        __syncthreads();
        tmp[threadIdx.x] += t;
        __syncthreads();
    }
    if (i < n) excl[i] = tmp[threadIdx.x] - v;   // exclusive within block
    if (threadIdx.x == 255) bsum[blockIdx.x] = tmp[255];
}

__global__ void k_scan_partials(int* bsum, int nb) {   // nb <= 512
    __shared__ int tmp[512];
    int t = threadIdx.x;
    int v = (t < nb) ? bsum[t] : 0;
    tmp[t] = v;
    __syncthreads();
    for (int off = 1; off < 512; off <<= 1) {
        int u = (t >= off) ? tmp[t - off] : 0;
        __syncthreads();
        tmp[t] += u;
        __syncthreads();
    }
    if (t < nb) bsum[t] = tmp[t] - v;  // exclusive block offsets
}

__global__ void k_scan_finish(int* excl, const int* __restrict__ bsum, int* cursor,
                              int n, int total) {
    int i = blockIdx.x * blockDim.x + threadIdx.x;
    if (i < n) {
        int r = excl[i] + bsum[i >> 8];
        excl[i] = r;
        cursor[i] = r;
    }
    if (i == 0) excl[n] = total;
}

__global__ void k_scatter_self(int* cursor, int* csr, int n) {
    int i = blockIdx.x * blockDim.x + threadIdx.x;
    if (i < n) {
        int p = atomicAdd(&cursor[i], 1);
        csr[p] = i;
    }
}

__global__ void k_scatter_edges(const int* __restrict__ ei, int* cursor, int* csr, int E) {
    int i = blockIdx.x * blockDim.x + threadIdx.x;
    if (i < E) {
        int s = ei[i];
        int d = ei[E + i];
        int p = atomicAdd(&cursor[d], 1);
        csr[p] = s;
    }
}

// ---------------- per-layer: GEMM + attention projections ----------------
// wave-per-row: lane = output col. h[row,lane] = sum_k x_eff[row,k] * W[k,lane]
// x_eff = relu(x) if do_relu (bias already folded into x by previous aggr).
__global__ void k_gemm_al(const float* __restrict__ x, int fin, int do_relu,
                          const float* __restrict__ W,
                          const float* __restrict__ as_, const float* __restrict__ ad_,
                          float* __restrict__ h, float* __restrict__ als, float* __restrict__ ald,
                          int n) {
    int wid = threadIdx.x >> 6, lane = threadIdx.x & 63;
    int row = blockIdx.x * (blockDim.x >> 6) + wid;
    if (row >= n) return;
    const float* xr = x + (size_t)row * fin;
    float acc = 0.f;
    for (int k = 0; k < fin; k += 4) {
        float4 xv = *reinterpret_cast<const float4*>(xr + k);
        if (do_relu) {
            xv.x = fmaxf(xv.x, 0.f); xv.y = fmaxf(xv.y, 0.f);
            xv.z = fmaxf(xv.z, 0.f); xv.w = fmaxf(xv.w, 0.f);
        }
        acc = fmaf(xv.x, W[(k + 0) * DIM + lane], acc);
        acc = fmaf(xv.y, W[(k + 1) * DIM + lane], acc);
        acc = fmaf(xv.z, W[(k + 2) * DIM + lane], acc);
        acc = fmaf(xv.w, W[(k + 3) * DIM + lane], acc);
    }
    h[(size_t)row * DIM + lane] = acc;
    float ps = acc * as_[lane];
    float pd = acc * ad_[lane];
    for (int off = 32; off; off >>= 1) {
        ps += __shfl_xor(ps, off);
        pd += __shfl_xor(pd, off);
    }
    if (lane == 0) { als[row] = ps; ald[row] = pd; }
}

// ---------------- per-layer: online-softmax aggregation (atomic-free) ----------------
// wave per destination node; lane = feature dim.
__global__ void k_node_aggr(const int* __restrict__ row_ptr, const int* __restrict__ csr,
                            const float* __restrict__ als, const float* __restrict__ ald,
                            const float* __restrict__ h, const float* __restrict__ bias,
                            float* __restrict__ out, int n) {
    int wid = threadIdx.x >> 6, lane = threadIdx.x & 63;
    int node = blockIdx.x * (blockDim.x >> 6) + wid;
    if (node >= n) return;
    int beg = row_ptr[node], end = row_ptr[node + 1];
    float adv = ald[node];
    float m = -INFINITY, ssum = 0.f, acc = 0.f;
    for (int p = beg; p < end; ++p) {
        int s = csr[p];
        float e = leaky(als[s] + adv);          // wave-uniform
        float hv = h[(size_t)s * DIM + lane];   // coalesced 256B gather
        if (e > m) {                            // wave-uniform branch
            float sc = __expf(m - e);           // exp(-inf)=0 on first edge
            ssum *= sc; acc *= sc; m = e;
        }
        float w = __expf(e - m);
        ssum += w;
        acc = fmaf(w, hv, acc);
    }
    out[(size_t)node * DIM + lane] = acc / ssum + bias[lane];
}

extern "C" void kernel_launch(void* const* d_in, const int* in_sizes, int n_in,
                              void* d_out, int out_size, void* d_ws, size_t ws_size,
                              hipStream_t stream) {
    const float* x = (const float*)d_in[0];
    const int* ei = (const int*)d_in[1];   // harness converts integer inputs to int32
    const int n = out_size / DIM;          // 100000
    const int E = in_sizes[1] / 2;         // 1600000
    const int fin0 = in_sizes[0] / n;      // 128
    const int total_edges = E + n;

    const float *W[3], *as_[3], *ad_[3], *b[3];
    for (int l = 0; l < 3; ++l) {
        W[l]  = (const float*)d_in[2 + 4 * l];
        as_[l] = (const float*)d_in[3 + 4 * l];
        ad_[l] = (const float*)d_in[4 + 4 * l];
        b[l]  = (const float*)d_in[5 + 4 * l];
    }

    // workspace carve (256B aligned). Inter-layer activations live in d_out
    // (read and written by disjoint kernels; fully overwritten by final layer).
    char* ws = (char*)d_ws;
    size_t off = 0;
    auto alloc = [&](size_t bytes) {
        void* p = ws + off;
        off = (off + bytes + 255) & ~(size_t)255;
        return p;
    };
    int* deg     = (int*)alloc((size_t)n * 4);
    int* row_ptr = (int*)alloc((size_t)(n + 1) * 4);
    int* cursor  = (int*)alloc((size_t)n * 4);
    int* bsum    = (int*)alloc(512 * 4);
    int* csr     = (int*)alloc((size_t)total_edges * 4);
    float* h     = (float*)alloc((size_t)n * DIM * 4);
    float* als   = (float*)alloc((size_t)n * 4);
    float* ald   = (float*)alloc((size_t)n * 4);
    float* buf   = (float*)d_out;          // inter-layer activations

    const int nbn = (n + 255) / 256;       // 391 (<=512 for scan_partials)
    const int nbe = (E + 255) / 256;

    // ---- CSR build (once; shared by all 3 layers) ----
    k_deg_init<<<nbn, 256, 0, stream>>>(deg, n);
    k_deg_count<<<nbe, 256, 0, stream>>>(ei, deg, E);
    k_scan_block<<<nbn, 256, 0, stream>>>(deg, row_ptr, bsum, n);
    k_scan_partials<<<1, 512, 0, stream>>>(bsum, nbn);
    k_scan_finish<<<nbn, 256, 0, stream>>>(row_ptr, bsum, cursor, n, total_edges);
    k_scatter_self<<<nbn, 256, 0, stream>>>(cursor, csr, n);
    k_scatter_edges<<<nbe, 256, 0, stream>>>(ei, cursor, csr, E);

    // ---- 3 GAT layers ----
    const int wave_blocks = (n + 3) / 4;   // 4 waves (rows/nodes) per 256-thread block
    const float* xin = x;
    int fin = fin0;
    for (int l = 0; l < 3; ++l) {
        k_gemm_al<<<wave_blocks, 256, 0, stream>>>(xin, fin, (l > 0) ? 1 : 0,
                                                   W[l], as_[l], ad_[l], h, als, ald, n);
        float* dst = (l == 2) ? (float*)d_out : buf;
        k_node_aggr<<<wave_blocks, 256, 0, stream>>>(row_ptr, csr, als, ald, h, b[l], dst, n);
        xin = buf;
        fin = DIM;
    }
}

// Round 3
// 1092.335 us; speedup vs baseline: 1.0186x; 1.0186x over previous
//
#include <hip/hip_runtime.h>
#include <math.h>

#define DIM 64

__device__ __forceinline__ float leaky(float e) { return e > 0.f ? e : 0.2f * e; }

// ---------------- CSR build ----------------
__global__ void k_deg_init(int* deg, int n) {
    int i = blockIdx.x * blockDim.x + threadIdx.x;
    if (i < n) deg[i] = 1;  // self loop
}

__global__ void k_deg_count(const int* __restrict__ ei, int* deg, int E) {
    int i = blockIdx.x * blockDim.x + threadIdx.x;
    if (i < E) atomicAdd(&deg[ei[E + i]], 1);
}

__global__ void k_scan_block(const int* __restrict__ deg, int* excl, int* bsum, int n) {
    __shared__ int tmp[256];
    int i = blockIdx.x * 256 + threadIdx.x;
    int v = (i < n) ? deg[i] : 0;
    tmp[threadIdx.x] = v;
    __syncthreads();
    for (int off = 1; off < 256; off <<= 1) {
        int t = (threadIdx.x >= off) ? tmp[threadIdx.x - off] : 0;
        __syncthreads();
        tmp[threadIdx.x] += t;
        __syncthreads();
    }
    if (i < n) excl[i] = tmp[threadIdx.x] - v;   // exclusive within block
    if (threadIdx.x == 255) bsum[blockIdx.x] = tmp[255];
}

__global__ void k_scan_partials(int* bsum, int nb) {   // nb <= 512
    __shared__ int tmp[512];
    int t = threadIdx.x;
    int v = (t < nb) ? bsum[t] : 0;
    tmp[t] = v;
    __syncthreads();
    for (int off = 1; off < 512; off <<= 1) {
        int u = (t >= off) ? tmp[t - off] : 0;
        __syncthreads();
        tmp[t] += u;
        __syncthreads();
    }
    if (t < nb) bsum[t] = tmp[t] - v;  // exclusive block offsets
}

__global__ void k_scan_finish(int* excl, const int* __restrict__ bsum, int* cursor,
                              int n, int total) {
    int i = blockIdx.x * blockDim.x + threadIdx.x;
    if (i < n) {
        int r = excl[i] + bsum[i >> 8];
        excl[i] = r;
        cursor[i] = r;
    }
    if (i == 0) excl[n] = total;
}

__global__ void k_scatter_self(int* cursor, int* csr, int n) {
    int i = blockIdx.x * blockDim.x + threadIdx.x;
    if (i < n) {
        int p = atomicAdd(&cursor[i], 1);
        csr[p] = i;
    }
}

__global__ void k_scatter_edges(const int* __restrict__ ei, int* cursor, int* csr, int E) {
    int i = blockIdx.x * blockDim.x + threadIdx.x;
    if (i < E) {
        int s = ei[i];
        int d = ei[E + i];
        int p = atomicAdd(&cursor[d], 1);
        csr[p] = s;
    }
}

// ---------------- per-layer: LDS-tiled GEMM + attention projections ----------------
// Block (256 thr) computes a BM x 64 tile of h = x_eff @ W.
// Thread (rt = tid>>4, ct = tid&15) owns rows rt*RPT..+RPT, cols ct*4..+4.
// Epilogue: als/ald row-dots fused via width-16 shuffle reduce.
template <int FIN, int BM, int RPT>
__global__ __launch_bounds__(256) void k_gemm_al(
        const float* __restrict__ x, int do_relu,
        const float* __restrict__ W,
        const float* __restrict__ as_, const float* __restrict__ ad_,
        float* __restrict__ h, float* __restrict__ als, float* __restrict__ ald,
        int n) {
    __shared__ float ws[FIN * 64];
    __shared__ float xs[BM * (FIN + 1)];

    const int tid = threadIdx.x;
    const int row0 = blockIdx.x * BM;

    // stage W (FIN x 64) as float4
    for (int i = tid; i < FIN * 16; i += 256) {
        *reinterpret_cast<float4*>(&ws[i * 4]) =
            *reinterpret_cast<const float4*>(&W[i * 4]);
    }
    // stage x tile (BM x FIN), padded stride FIN+1, relu on input if needed
    for (int i = tid; i < BM * (FIN / 4); i += 256) {
        int r = i / (FIN / 4);
        int kq = i - r * (FIN / 4);
        int grow = row0 + r;
        float4 v = make_float4(0.f, 0.f, 0.f, 0.f);
        if (grow < n)
            v = *reinterpret_cast<const float4*>(&x[(size_t)grow * FIN + kq * 4]);
        if (do_relu) {
            v.x = fmaxf(v.x, 0.f); v.y = fmaxf(v.y, 0.f);
            v.z = fmaxf(v.z, 0.f); v.w = fmaxf(v.w, 0.f);
        }
        float* dst = &xs[r * (FIN + 1) + kq * 4];
        dst[0] = v.x; dst[1] = v.y; dst[2] = v.z; dst[3] = v.w;
    }
    __syncthreads();

    const int rt = tid >> 4, ct = tid & 15;
    const int r0 = rt * RPT, c0 = ct * 4;

    float acc[RPT][4];
#pragma unroll
    for (int i = 0; i < RPT; ++i)
#pragma unroll
        for (int j = 0; j < 4; ++j) acc[i][j] = 0.f;

#pragma unroll
    for (int k = 0; k < FIN; ++k) {
        float4 wv = *reinterpret_cast<const float4*>(&ws[k * 64 + c0]);
#pragma unroll
        for (int i = 0; i < RPT; ++i) {
            float xv = xs[(r0 + i) * (FIN + 1) + k];
            acc[i][0] = fmaf(xv, wv.x, acc[i][0]);
            acc[i][1] = fmaf(xv, wv.y, acc[i][1]);
            acc[i][2] = fmaf(xv, wv.z, acc[i][2]);
            acc[i][3] = fmaf(xv, wv.w, acc[i][3]);
        }
    }

    // store h tile + fused attention projections
    float4 asv = *reinterpret_cast<const float4*>(&as_[c0]);
    float4 adv = *reinterpret_cast<const float4*>(&ad_[c0]);
#pragma unroll
    for (int i = 0; i < RPT; ++i) {
        int grow = row0 + r0 + i;
        if (grow < n) {
            *reinterpret_cast<float4*>(&h[(size_t)grow * 64 + c0]) =
                make_float4(acc[i][0], acc[i][1], acc[i][2], acc[i][3]);
        }
        float ps = acc[i][0] * asv.x + acc[i][1] * asv.y +
                   acc[i][2] * asv.z + acc[i][3] * asv.w;
        float pd = acc[i][0] * adv.x + acc[i][1] * adv.y +
                   acc[i][2] * adv.z + acc[i][3] * adv.w;
#pragma unroll
        for (int off = 1; off < 16; off <<= 1) {
            ps += __shfl_xor(ps, off);
            pd += __shfl_xor(pd, off);
        }
        if (ct == 0 && grow < n) { als[grow] = ps; ald[grow] = pd; }
    }
}

// ---------------- per-layer: online-softmax aggregation (atomic-free) ----------------
// wave per destination node; lane = feature dim.
__global__ void k_node_aggr(const int* __restrict__ row_ptr, const int* __restrict__ csr,
                            const float* __restrict__ als, const float* __restrict__ ald,
                            const float* __restrict__ h, const float* __restrict__ bias,
                            float* __restrict__ out, int n) {
    int wid = threadIdx.x >> 6, lane = threadIdx.x & 63;
    int node = blockIdx.x * (blockDim.x >> 6) + wid;
    if (node >= n) return;
    int beg = row_ptr[node], end = row_ptr[node + 1];
    float adv = ald[node];
    float m = -INFINITY, ssum = 0.f, acc = 0.f;
    for (int p = beg; p < end; ++p) {
        int s = csr[p];
        float e = leaky(als[s] + adv);          // wave-uniform
        float hv = h[(size_t)s * DIM + lane];   // coalesced 256B gather
        if (e > m) {                            // wave-uniform branch
            float sc = __expf(m - e);           // exp(-inf)=0 on first edge
            ssum *= sc; acc *= sc; m = e;
        }
        float w = __expf(e - m);
        ssum += w;
        acc = fmaf(w, hv, acc);
    }
    out[(size_t)node * DIM + lane] = acc / ssum + bias[lane];
}

extern "C" void kernel_launch(void* const* d_in, const int* in_sizes, int n_in,
                              void* d_out, int out_size, void* d_ws, size_t ws_size,
                              hipStream_t stream) {
    const float* x = (const float*)d_in[0];
    const int* ei = (const int*)d_in[1];   // harness converts integer inputs to int32
    const int n = out_size / DIM;          // 100000
    const int E = in_sizes[1] / 2;         // 1600000
    const int total_edges = E + n;

    const float *W[3], *as_[3], *ad_[3], *b[3];
    for (int l = 0; l < 3; ++l) {
        W[l]  = (const float*)d_in[2 + 4 * l];
        as_[l] = (const float*)d_in[3 + 4 * l];
        ad_[l] = (const float*)d_in[4 + 4 * l];
        b[l]  = (const float*)d_in[5 + 4 * l];
    }

    // workspace carve (256B aligned). Inter-layer activations live in d_out
    // (read and written by disjoint kernels; fully overwritten by final layer).
    char* ws = (char*)d_ws;
    size_t off = 0;
    auto alloc = [&](size_t bytes) {
        void* p = ws + off;
        off = (off + bytes + 255) & ~(size_t)255;
        return p;
    };
    int* deg     = (int*)alloc((size_t)n * 4);
    int* row_ptr = (int*)alloc((size_t)(n + 1) * 4);
    int* cursor  = (int*)alloc((size_t)n * 4);
    int* bsum    = (int*)alloc(512 * 4);
    int* csr     = (int*)alloc((size_t)total_edges * 4);
    float* h     = (float*)alloc((size_t)n * DIM * 4);
    float* als   = (float*)alloc((size_t)n * 4);
    float* ald   = (float*)alloc((size_t)n * 4);
    float* buf   = (float*)d_out;          // inter-layer activations

    const int nbn = (n + 255) / 256;       // 391 (<=512 for scan_partials)
    const int nbe = (E + 255) / 256;

    // ---- CSR build (once; shared by all 3 layers) ----
    k_deg_init<<<nbn, 256, 0, stream>>>(deg, n);
    k_deg_count<<<nbe, 256, 0, stream>>>(ei, deg, E);
    k_scan_block<<<nbn, 256, 0, stream>>>(deg, row_ptr, bsum, n);
    k_scan_partials<<<1, 512, 0, stream>>>(bsum, nbn);
    k_scan_finish<<<nbn, 256, 0, stream>>>(row_ptr, bsum, cursor, n, total_edges);
    k_scatter_self<<<nbn, 256, 0, stream>>>(cursor, csr, n);
    k_scatter_edges<<<nbe, 256, 0, stream>>>(ei, cursor, csr, E);

    // ---- 3 GAT layers ----
    const int aggr_blocks = (n + 3) / 4;   // 4 waves (nodes) per 256-thread block
    const float* xin = x;
    for (int l = 0; l < 3; ++l) {
        if (l == 0) {
            k_gemm_al<128, 32, 2><<<(n + 31) / 32, 256, 0, stream>>>(
                xin, 0, W[l], as_[l], ad_[l], h, als, ald, n);
        } else {
            k_gemm_al<64, 64, 4><<<(n + 63) / 64, 256, 0, stream>>>(
                xin, 1, W[l], as_[l], ad_[l], h, als, ald, n);
        }
        float* dst = (l == 2) ? (float*)d_out : buf;
        k_node_aggr<<<aggr_blocks, 256, 0, stream>>>(row_ptr, csr, als, ald, h, b[l], dst, n);
        xin = buf;
    }
}

// Round 4
// 777.340 us; speedup vs baseline: 1.4314x; 1.4052x over previous
//
#include <hip/hip_runtime.h>
#include <math.h>

#define DIM 64

__device__ __forceinline__ float leaky(float e) { return e > 0.f ? e : 0.2f * e; }

// ---------------- CSR build ----------------
__global__ void k_deg_init(int* deg, int n) {
    int i = blockIdx.x * blockDim.x + threadIdx.x;
    if (i < n) deg[i] = 1;  // self loop
}

__global__ void k_deg_count(const int* __restrict__ ei, int* deg, int E) {
    int i = blockIdx.x * blockDim.x + threadIdx.x;
    if (i < E) atomicAdd(&deg[ei[E + i]], 1);
}

__global__ void k_scan_block(const int* __restrict__ deg, int* excl, int* bsum, int n) {
    __shared__ int tmp[256];
    int i = blockIdx.x * 256 + threadIdx.x;
    int v = (i < n) ? deg[i] : 0;
    tmp[threadIdx.x] = v;
    __syncthreads();
    for (int off = 1; off < 256; off <<= 1) {
        int t = (threadIdx.x >= off) ? tmp[threadIdx.x - off] : 0;
        __syncthreads();
        tmp[threadIdx.x] += t;
        __syncthreads();
    }
    if (i < n) excl[i] = tmp[threadIdx.x] - v;   // exclusive within block
    if (threadIdx.x == 255) bsum[blockIdx.x] = tmp[255];
}

__global__ void k_scan_partials(int* bsum, int nb) {   // nb <= 512
    __shared__ int tmp[512];
    int t = threadIdx.x;
    int v = (t < nb) ? bsum[t] : 0;
    tmp[t] = v;
    __syncthreads();
    for (int off = 1; off < 512; off <<= 1) {
        int u = (t >= off) ? tmp[t - off] : 0;
        __syncthreads();
        tmp[t] += u;
        __syncthreads();
    }
    if (t < nb) bsum[t] = tmp[t] - v;  // exclusive block offsets
}

__global__ void k_scan_finish(int* excl, const int* __restrict__ bsum, int* cursor,
                              int n, int total) {
    int i = blockIdx.x * blockDim.x + threadIdx.x;
    if (i < n) {
        int r = excl[i] + bsum[i >> 8];
        excl[i] = r;
        cursor[i] = r;
    }
    if (i == 0) excl[n] = total;
}

__global__ void k_scatter_self(int* cursor, int* csr, int n) {
    int i = blockIdx.x * blockDim.x + threadIdx.x;
    if (i < n) {
        int p = atomicAdd(&cursor[i], 1);
        csr[p] = i;
    }
}

__global__ void k_scatter_edges(const int* __restrict__ ei, int* cursor, int* csr, int E) {
    int i = blockIdx.x * blockDim.x + threadIdx.x;
    if (i < E) {
        int s = ei[i];
        int d = ei[E + i];
        int p = atomicAdd(&cursor[d], 1);
        csr[p] = s;
    }
}

// ---------------- per-layer: K-tiled LDS GEMM + attention projections ----------------
// Block (256 thr) computes a 64 x 64 tile of h = x_eff @ W, K staged in KT=64 chunks.
// Thread (rt = tid>>4, ct = tid&15) owns rows rt*4..+4, cols ct*4..+4 (16 acc regs).
// LDS: ws[KT][64] (16KB), xs[64][KT+1] stride 65 (16.25KB) -> 33KB, 4 blocks/CU.
// Bank math: xs stores bank=(r+4kq+j)%32 2-way free; xs reads bank=(4rt+i+k)%32
// 2-way broadcast; ws reads 16 distinct float4 = 2-way. All conflict-free.
// __launch_bounds__(256,4) caps VGPR<=128; unroll 4 keeps live set ~60 regs (no spill).
template <int FIN>
__global__ __launch_bounds__(256, 4) void k_gemm_al(
        const float* __restrict__ x, int do_relu,
        const float* __restrict__ W,
        const float* __restrict__ as_, const float* __restrict__ ad_,
        float* __restrict__ h, float* __restrict__ als, float* __restrict__ ald,
        int n) {
    constexpr int KT = 64;
    constexpr int BM = 64;
    __shared__ float ws[KT * 64];        // [k][col]
    __shared__ float xs[BM * (KT + 1)];  // [row][k], stride 65

    const int tid = threadIdx.x;
    const int row0 = blockIdx.x * BM;
    const int rt = tid >> 4, ct = tid & 15;
    const int r0 = rt * 4, c0 = ct * 4;

    float acc[4][4];
#pragma unroll
    for (int i = 0; i < 4; ++i)
#pragma unroll
        for (int j = 0; j < 4; ++j) acc[i][j] = 0.f;

    for (int kt = 0; kt < FIN; kt += KT) {
        // stage W rows kt..kt+KT (KT*64 floats = 1024 float4, 4 per thread)
#pragma unroll
        for (int p = 0; p < KT * 16 / 256; ++p) {
            int i = tid + p * 256;
            *reinterpret_cast<float4*>(&ws[i * 4]) =
                *reinterpret_cast<const float4*>(&W[kt * 64 + i * 4]);
        }
        // stage x tile (BM rows x KT k's), row-major stride 65
#pragma unroll
        for (int p = 0; p < BM * (KT / 4) / 256; ++p) {
            int i = tid + p * 256;
            int r = i >> 4;          // 16 quads per row
            int kq = i & 15;
            int grow = row0 + r;
            float4 v = make_float4(0.f, 0.f, 0.f, 0.f);
            if (grow < n)
                v = *reinterpret_cast<const float4*>(&x[(size_t)grow * FIN + kt + kq * 4]);
            if (do_relu) {
                v.x = fmaxf(v.x, 0.f); v.y = fmaxf(v.y, 0.f);
                v.z = fmaxf(v.z, 0.f); v.w = fmaxf(v.w, 0.f);
            }
            float* dst = &xs[r * (KT + 1) + kq * 4];
            dst[0] = v.x; dst[1] = v.y; dst[2] = v.z; dst[3] = v.w;
        }
        __syncthreads();

#pragma unroll 4
        for (int k = 0; k < KT; ++k) {
            float4 wv = *reinterpret_cast<const float4*>(&ws[k * 64 + c0]);
            float xv0 = xs[(r0 + 0) * (KT + 1) + k];
            float xv1 = xs[(r0 + 1) * (KT + 1) + k];
            float xv2 = xs[(r0 + 2) * (KT + 1) + k];
            float xv3 = xs[(r0 + 3) * (KT + 1) + k];
            acc[0][0] = fmaf(xv0, wv.x, acc[0][0]);
            acc[0][1] = fmaf(xv0, wv.y, acc[0][1]);
            acc[0][2] = fmaf(xv0, wv.z, acc[0][2]);
            acc[0][3] = fmaf(xv0, wv.w, acc[0][3]);
            acc[1][0] = fmaf(xv1, wv.x, acc[1][0]);
            acc[1][1] = fmaf(xv1, wv.y, acc[1][1]);
            acc[1][2] = fmaf(xv1, wv.z, acc[1][2]);
            acc[1][3] = fmaf(xv1, wv.w, acc[1][3]);
            acc[2][0] = fmaf(xv2, wv.x, acc[2][0]);
            acc[2][1] = fmaf(xv2, wv.y, acc[2][1]);
            acc[2][2] = fmaf(xv2, wv.z, acc[2][2]);
            acc[2][3] = fmaf(xv2, wv.w, acc[2][3]);
            acc[3][0] = fmaf(xv3, wv.x, acc[3][0]);
            acc[3][1] = fmaf(xv3, wv.y, acc[3][1]);
            acc[3][2] = fmaf(xv3, wv.z, acc[3][2]);
            acc[3][3] = fmaf(xv3, wv.w, acc[3][3]);
        }
        __syncthreads();
    }

    // store h tile + fused attention projections (width-16 shuffle reduce)
    float4 asv = *reinterpret_cast<const float4*>(&as_[c0]);
    float4 adv = *reinterpret_cast<const float4*>(&ad_[c0]);
#pragma unroll
    for (int i = 0; i < 4; ++i) {
        int grow = row0 + r0 + i;
        if (grow < n) {
            *reinterpret_cast<float4*>(&h[(size_t)grow * 64 + c0]) =
                make_float4(acc[i][0], acc[i][1], acc[i][2], acc[i][3]);
        }
        float ps = acc[i][0] * asv.x + acc[i][1] * asv.y +
                   acc[i][2] * asv.z + acc[i][3] * asv.w;
        float pd = acc[i][0] * adv.x + acc[i][1] * adv.y +
                   acc[i][2] * adv.z + acc[i][3] * adv.w;
#pragma unroll
        for (int off = 1; off < 16; off <<= 1) {
            ps += __shfl_xor(ps, off);
            pd += __shfl_xor(pd, off);
        }
        if (ct == 0 && grow < n) { als[grow] = ps; ald[grow] = pd; }
    }
}

// ---------------- per-layer: online-softmax aggregation (atomic-free) ----------------
// wave per destination node; lane = feature dim.
__global__ void k_node_aggr(const int* __restrict__ row_ptr, const int* __restrict__ csr,
                            const float* __restrict__ als, const float* __restrict__ ald,
                            const float* __restrict__ h, const float* __restrict__ bias,
                            float* __restrict__ out, int n) {
    int wid = threadIdx.x >> 6, lane = threadIdx.x & 63;
    int node = blockIdx.x * (blockDim.x >> 6) + wid;
    if (node >= n) return;
    int beg = row_ptr[node], end = row_ptr[node + 1];
    float adv = ald[node];
    float m = -INFINITY, ssum = 0.f, acc = 0.f;
    for (int p = beg; p < end; ++p) {
        int s = csr[p];
        float e = leaky(als[s] + adv);          // wave-uniform
        float hv = h[(size_t)s * DIM + lane];   // coalesced 256B gather
        if (e > m) {                            // wave-uniform branch
            float sc = __expf(m - e);           // exp(-inf)=0 on first edge
            ssum *= sc; acc *= sc; m = e;
        }
        float w = __expf(e - m);
        ssum += w;
        acc = fmaf(w, hv, acc);
    }
    out[(size_t)node * DIM + lane] = acc / ssum + bias[lane];
}

extern "C" void kernel_launch(void* const* d_in, const int* in_sizes, int n_in,
                              void* d_out, int out_size, void* d_ws, size_t ws_size,
                              hipStream_t stream) {
    const float* x = (const float*)d_in[0];
    const int* ei = (const int*)d_in[1];   // harness converts integer inputs to int32
    const int n = out_size / DIM;          // 100000
    const int E = in_sizes[1] / 2;         // 1600000
    const int total_edges = E + n;

    const float *W[3], *as_[3], *ad_[3], *b[3];
    for (int l = 0; l < 3; ++l) {
        W[l]  = (const float*)d_in[2 + 4 * l];
        as_[l] = (const float*)d_in[3 + 4 * l];
        ad_[l] = (const float*)d_in[4 + 4 * l];
        b[l]  = (const float*)d_in[5 + 4 * l];
    }

    // workspace carve (256B aligned). Inter-layer activations live in d_out
    // (read and written by disjoint kernels; fully overwritten by final layer).
    char* ws = (char*)d_ws;
    size_t off = 0;
    auto alloc = [&](size_t bytes) {
        void* p = ws + off;
        off = (off + bytes + 255) & ~(size_t)255;
        return p;
    };
    int* deg     = (int*)alloc((size_t)n * 4);
    int* row_ptr = (int*)alloc((size_t)(n + 1) * 4);
    int* cursor  = (int*)alloc((size_t)n * 4);
    int* bsum    = (int*)alloc(512 * 4);
    int* csr     = (int*)alloc((size_t)total_edges * 4);
    float* h     = (float*)alloc((size_t)n * DIM * 4);
    float* als   = (float*)alloc((size_t)n * 4);
    float* ald   = (float*)alloc((size_t)n * 4);
    float* buf   = (float*)d_out;          // inter-layer activations

    const int nbn = (n + 255) / 256;       // 391 (<=512 for scan_partials)
    const int nbe = (E + 255) / 256;

    // ---- CSR build (once; shared by all 3 layers) ----
    k_deg_init<<<nbn, 256, 0, stream>>>(deg, n);
    k_deg_count<<<nbe, 256, 0, stream>>>(ei, deg, E);
    k_scan_block<<<nbn, 256, 0, stream>>>(deg, row_ptr, bsum, n);
    k_scan_partials<<<1, 512, 0, stream>>>(bsum, nbn);
    k_scan_finish<<<nbn, 256, 0, stream>>>(row_ptr, bsum, cursor, n, total_edges);
    k_scatter_self<<<nbn, 256, 0, stream>>>(cursor, csr, n);
    k_scatter_edges<<<nbe, 256, 0, stream>>>(ei, cursor, csr, E);

    // ---- 3 GAT layers ----
    const int aggr_blocks = (n + 3) / 4;   // 4 waves (nodes) per 256-thread block
    const int gemm_blocks = (n + 63) / 64;
    const float* xin = x;
    for (int l = 0; l < 3; ++l) {
        if (l == 0) {
            k_gemm_al<128><<<gemm_blocks, 256, 0, stream>>>(
                xin, 0, W[l], as_[l], ad_[l], h, als, ald, n);
        } else {
            k_gemm_al<64><<<gemm_blocks, 256, 0, stream>>>(
                xin, 1, W[l], as_[l], ad_[l], h, als, ald, n);
        }
        float* dst = (l == 2) ? (float*)d_out : buf;
        k_node_aggr<<<aggr_blocks, 256, 0, stream>>>(row_ptr, csr, als, ald, h, b[l], dst, n);
        xin = buf;
    }
}

// Round 5
// 745.218 us; speedup vs baseline: 1.4931x; 1.0431x over previous
//
#include <hip/hip_runtime.h>
#include <math.h>

#define DIM 64

__device__ __forceinline__ float leaky(float e) { return e > 0.f ? e : 0.2f * e; }

// monotonic float<->uint key for atomicMax-based float max
__device__ __forceinline__ unsigned fkey(float f) {
    unsigned u = __float_as_uint(f);
    return (u & 0x80000000u) ? ~u : (u | 0x80000000u);
}
__device__ __forceinline__ float fkey_inv(unsigned k) {
    return __uint_as_float((k & 0x80000000u) ? (k ^ 0x80000000u) : ~k);
}

// ---------------- CSR build ----------------
__global__ void k_deg_init(int* deg, int n) {
    int i = blockIdx.x * blockDim.x + threadIdx.x;
    if (i < n) deg[i] = 1;  // self loop
}

__global__ void k_deg_count(const int* __restrict__ ei, int* deg, int E) {
    int i = blockIdx.x * blockDim.x + threadIdx.x;
    if (i < E) atomicAdd(&deg[ei[E + i]], 1);
}

__global__ void k_scan_block(const int* __restrict__ deg, int* excl, int* bsum, int n) {
    __shared__ int tmp[256];
    int i = blockIdx.x * 256 + threadIdx.x;
    int v = (i < n) ? deg[i] : 0;
    tmp[threadIdx.x] = v;
    __syncthreads();
    for (int off = 1; off < 256; off <<= 1) {
        int t = (threadIdx.x >= off) ? tmp[threadIdx.x - off] : 0;
        __syncthreads();
        tmp[threadIdx.x] += t;
        __syncthreads();
    }
    if (i < n) excl[i] = tmp[threadIdx.x] - v;   // exclusive within block
    if (threadIdx.x == 255) bsum[blockIdx.x] = tmp[255];
}

__global__ void k_scan_partials(int* bsum, int nb) {   // nb <= 512
    __shared__ int tmp[512];
    int t = threadIdx.x;
    int v = (t < nb) ? bsum[t] : 0;
    tmp[t] = v;
    __syncthreads();
    for (int off = 1; off < 512; off <<= 1) {
        int u = (t >= off) ? tmp[t - off] : 0;
        __syncthreads();
        tmp[t] += u;
        __syncthreads();
    }
    if (t < nb) bsum[t] = tmp[t] - v;  // exclusive block offsets
}

__global__ void k_scan_finish(int* excl, const int* __restrict__ bsum, int* cursor,
                              int n, int total) {
    int i = blockIdx.x * blockDim.x + threadIdx.x;
    if (i < n) {
        int r = excl[i] + bsum[i >> 8];
        excl[i] = r;
        cursor[i] = r;
    }
    if (i == 0) excl[n] = total;
}

__global__ void k_scatter_self(int* cursor, int* csr, int* dstv, int n) {
    int i = blockIdx.x * blockDim.x + threadIdx.x;
    if (i < n) {
        int p = atomicAdd(&cursor[i], 1);
        csr[p] = i;
        dstv[p] = i;
    }
}

__global__ void k_scatter_edges(const int* __restrict__ ei, int* cursor, int* csr,
                                int* dstv, int E) {
    int i = blockIdx.x * blockDim.x + threadIdx.x;
    if (i < E) {
        int s = ei[i];
        int d = ei[E + i];
        int p = atomicAdd(&cursor[d], 1);
        csr[p] = s;
        dstv[p] = d;
    }
}

__global__ void k_fill_zero(unsigned* p, int n) {
    int i = blockIdx.x * blockDim.x + threadIdx.x;
    if (i < n) p[i] = 0u;   // key-space -inf
}

// ---------------- per-layer: K-tiled LDS GEMM + attention projections ----------------
// Block (256 thr) computes a 64 x 64 tile of h = x_eff @ W, K staged in KT=64 chunks.
// Thread (rt = tid>>4, ct = tid&15) owns rows rt*4..+4, cols ct*4..+4 (16 acc regs).
// LDS: ws[KT][64] (16KB), xs[64][KT+1] stride 65 (16.25KB) -> 33KB, 4 blocks/CU.
template <int FIN>
__global__ __launch_bounds__(256, 4) void k_gemm_al(
        const float* __restrict__ x, int do_relu,
        const float* __restrict__ W,
        const float* __restrict__ as_, const float* __restrict__ ad_,
        float* __restrict__ h, float* __restrict__ als, float* __restrict__ ald,
        int n) {
    constexpr int KT = 64;
    constexpr int BM = 64;
    __shared__ float ws[KT * 64];        // [k][col]
    __shared__ float xs[BM * (KT + 1)];  // [row][k], stride 65

    const int tid = threadIdx.x;
    const int row0 = blockIdx.x * BM;
    const int rt = tid >> 4, ct = tid & 15;
    const int r0 = rt * 4, c0 = ct * 4;

    float acc[4][4];
#pragma unroll
    for (int i = 0; i < 4; ++i)
#pragma unroll
        for (int j = 0; j < 4; ++j) acc[i][j] = 0.f;

    for (int kt = 0; kt < FIN; kt += KT) {
#pragma unroll
        for (int p = 0; p < KT * 16 / 256; ++p) {
            int i = tid + p * 256;
            *reinterpret_cast<float4*>(&ws[i * 4]) =
                *reinterpret_cast<const float4*>(&W[kt * 64 + i * 4]);
        }
#pragma unroll
        for (int p = 0; p < BM * (KT / 4) / 256; ++p) {
            int i = tid + p * 256;
            int r = i >> 4;          // 16 quads per row
            int kq = i & 15;
            int grow = row0 + r;
            float4 v = make_float4(0.f, 0.f, 0.f, 0.f);
            if (grow < n)
                v = *reinterpret_cast<const float4*>(&x[(size_t)grow * FIN + kt + kq * 4]);
            if (do_relu) {
                v.x = fmaxf(v.x, 0.f); v.y = fmaxf(v.y, 0.f);
                v.z = fmaxf(v.z, 0.f); v.w = fmaxf(v.w, 0.f);
            }
            float* dst = &xs[r * (KT + 1) + kq * 4];
            dst[0] = v.x; dst[1] = v.y; dst[2] = v.z; dst[3] = v.w;
        }
        __syncthreads();

#pragma unroll 4
        for (int k = 0; k < KT; ++k) {
            float4 wv = *reinterpret_cast<const float4*>(&ws[k * 64 + c0]);
            float xv0 = xs[(r0 + 0) * (KT + 1) + k];
            float xv1 = xs[(r0 + 1) * (KT + 1) + k];
            float xv2 = xs[(r0 + 2) * (KT + 1) + k];
            float xv3 = xs[(r0 + 3) * (KT + 1) + k];
            acc[0][0] = fmaf(xv0, wv.x, acc[0][0]);
            acc[0][1] = fmaf(xv0, wv.y, acc[0][1]);
            acc[0][2] = fmaf(xv0, wv.z, acc[0][2]);
            acc[0][3] = fmaf(xv0, wv.w, acc[0][3]);
            acc[1][0] = fmaf(xv1, wv.x, acc[1][0]);
            acc[1][1] = fmaf(xv1, wv.y, acc[1][1]);
            acc[1][2] = fmaf(xv1, wv.z, acc[1][2]);
            acc[1][3] = fmaf(xv1, wv.w, acc[1][3]);
            acc[2][0] = fmaf(xv2, wv.x, acc[2][0]);
            acc[2][1] = fmaf(xv2, wv.y, acc[2][1]);
            acc[2][2] = fmaf(xv2, wv.z, acc[2][2]);
            acc[2][3] = fmaf(xv2, wv.w, acc[2][3]);
            acc[3][0] = fmaf(xv3, wv.x, acc[3][0]);
            acc[3][1] = fmaf(xv3, wv.y, acc[3][1]);
            acc[3][2] = fmaf(xv3, wv.z, acc[3][2]);
            acc[3][3] = fmaf(xv3, wv.w, acc[3][3]);
        }
        __syncthreads();
    }

    float4 asv = *reinterpret_cast<const float4*>(&as_[c0]);
    float4 adv = *reinterpret_cast<const float4*>(&ad_[c0]);
#pragma unroll
    for (int i = 0; i < 4; ++i) {
        int grow = row0 + r0 + i;
        if (grow < n) {
            *reinterpret_cast<float4*>(&h[(size_t)grow * 64 + c0]) =
                make_float4(acc[i][0], acc[i][1], acc[i][2], acc[i][3]);
        }
        float ps = acc[i][0] * asv.x + acc[i][1] * asv.y +
                   acc[i][2] * asv.z + acc[i][3] * asv.w;
        float pd = acc[i][0] * adv.x + acc[i][1] * adv.y +
                   acc[i][2] * adv.z + acc[i][3] * adv.w;
#pragma unroll
        for (int off = 1; off < 16; off <<= 1) {
            ps += __shfl_xor(ps, off);
            pd += __shfl_xor(pd, off);
        }
        if (ct == 0 && grow < n) { als[grow] = ps; ald[grow] = pd; }
    }
}

// ---------------- per-layer: edge-parallel logits + exact segment max ----------------
__global__ void k_edge_logits(const int* __restrict__ csr, const int* __restrict__ dstv,
                              const float* __restrict__ als, const float* __restrict__ ald,
                              float* __restrict__ att, unsigned* __restrict__ mkey,
                              int total) {
    int p = blockIdx.x * blockDim.x + threadIdx.x;
    if (p >= total) return;
    int s = csr[p];
    int d = dstv[p];
    float e = leaky(als[s] + ald[d]);
    att[p] = e;
    atomicMax(&mkey[d], fkey(e));
}

// ---------------- per-layer: branch-free gather aggregation ----------------
// wave per destination node; lane = feature dim; 4 independent h-gathers in flight.
__global__ void k_node_aggr(const int* __restrict__ row_ptr, const int* __restrict__ csr,
                            const float* __restrict__ att, const unsigned* __restrict__ mkey,
                            const float* __restrict__ h, const float* __restrict__ bias,
                            float* __restrict__ out, int n) {
    int wid = threadIdx.x >> 6, lane = threadIdx.x & 63;
    int node = blockIdx.x * (blockDim.x >> 6) + wid;
    if (node >= n) return;
    int beg = row_ptr[node], end = row_ptr[node + 1];
    float m = fkey_inv(mkey[node]);
    float ssum = 0.f, acc = 0.f;
    int p = beg;
    for (; p + 4 <= end; p += 4) {
        int s0 = csr[p], s1 = csr[p + 1], s2 = csr[p + 2], s3 = csr[p + 3];
        float e0 = att[p], e1 = att[p + 1], e2 = att[p + 2], e3 = att[p + 3];
        float h0 = h[(size_t)s0 * DIM + lane];
        float h1 = h[(size_t)s1 * DIM + lane];
        float h2 = h[(size_t)s2 * DIM + lane];
        float h3 = h[(size_t)s3 * DIM + lane];
        float w0 = __expf(e0 - m), w1 = __expf(e1 - m);
        float w2 = __expf(e2 - m), w3 = __expf(e3 - m);
        ssum += (w0 + w1) + (w2 + w3);
        acc = fmaf(w0, h0, acc);
        acc = fmaf(w1, h1, acc);
        acc = fmaf(w2, h2, acc);
        acc = fmaf(w3, h3, acc);
    }
    for (; p < end; ++p) {
        int s = csr[p];
        float e = att[p];
        float hv = h[(size_t)s * DIM + lane];
        float w = __expf(e - m);
        ssum += w;
        acc = fmaf(w, hv, acc);
    }
    out[(size_t)node * DIM + lane] = acc / ssum + bias[lane];
}

extern "C" void kernel_launch(void* const* d_in, const int* in_sizes, int n_in,
                              void* d_out, int out_size, void* d_ws, size_t ws_size,
                              hipStream_t stream) {
    const float* x = (const float*)d_in[0];
    const int* ei = (const int*)d_in[1];   // harness converts integer inputs to int32
    const int n = out_size / DIM;          // 100000
    const int E = in_sizes[1] / 2;         // 1600000
    const int total_edges = E + n;

    const float *W[3], *as_[3], *ad_[3], *b[3];
    for (int l = 0; l < 3; ++l) {
        W[l]  = (const float*)d_in[2 + 4 * l];
        as_[l] = (const float*)d_in[3 + 4 * l];
        ad_[l] = (const float*)d_in[4 + 4 * l];
        b[l]  = (const float*)d_in[5 + 4 * l];
    }

    // workspace carve (256B aligned). Inter-layer activations live in d_out.
    char* ws = (char*)d_ws;
    size_t off = 0;
    auto alloc = [&](size_t bytes) {
        void* p = ws + off;
        off = (off + bytes + 255) & ~(size_t)255;
        return p;
    };
    int* deg      = (int*)alloc((size_t)n * 4);
    int* row_ptr  = (int*)alloc((size_t)(n + 1) * 4);
    int* cursor   = (int*)alloc((size_t)n * 4);
    int* bsum     = (int*)alloc(512 * 4);
    int* csr      = (int*)alloc((size_t)total_edges * 4);
    int* dstv     = (int*)alloc((size_t)total_edges * 4);
    float* att    = (float*)alloc((size_t)total_edges * 4);
    unsigned* mkey = (unsigned*)alloc((size_t)n * 4);
    float* h      = (float*)alloc((size_t)n * DIM * 4);
    float* als    = (float*)alloc((size_t)n * 4);
    float* ald    = (float*)alloc((size_t)n * 4);
    float* buf    = (float*)d_out;         // inter-layer activations

    const int nbn = (n + 255) / 256;       // 391 (<=512 for scan_partials)
    const int nbe = (E + 255) / 256;
    const int nbt = (total_edges + 255) / 256;

    // ---- CSR build (once; shared by all 3 layers) ----
    k_deg_init<<<nbn, 256, 0, stream>>>(deg, n);
    k_deg_count<<<nbe, 256, 0, stream>>>(ei, deg, E);
    k_scan_block<<<nbn, 256, 0, stream>>>(deg, row_ptr, bsum, n);
    k_scan_partials<<<1, 512, 0, stream>>>(bsum, nbn);
    k_scan_finish<<<nbn, 256, 0, stream>>>(row_ptr, bsum, cursor, n, total_edges);
    k_scatter_self<<<nbn, 256, 0, stream>>>(cursor, csr, dstv, n);
    k_scatter_edges<<<nbe, 256, 0, stream>>>(ei, cursor, csr, dstv, E);

    // ---- 3 GAT layers ----
    const int aggr_blocks = (n + 3) / 4;   // 4 waves (nodes) per 256-thread block
    const int gemm_blocks = (n + 63) / 64;
    const float* xin = x;
    for (int l = 0; l < 3; ++l) {
        if (l == 0) {
            k_gemm_al<128><<<gemm_blocks, 256, 0, stream>>>(
                xin, 0, W[l], as_[l], ad_[l], h, als, ald, n);
        } else {
            k_gemm_al<64><<<gemm_blocks, 256, 0, stream>>>(
                xin, 1, W[l], as_[l], ad_[l], h, als, ald, n);
        }
        k_fill_zero<<<nbn, 256, 0, stream>>>(mkey, n);
        k_edge_logits<<<nbt, 256, 0, stream>>>(csr, dstv, als, ald, att, mkey, total_edges);
        float* dst = (l == 2) ? (float*)d_out : buf;
        k_node_aggr<<<aggr_blocks, 256, 0, stream>>>(row_ptr, csr, att, mkey, h, b[l], dst, n);
        xin = buf;
    }
}